// Round 8
// baseline (1222.670 us; speedup 1.0000x reference)
//
#include <hip/hip_runtime.h>
#include <hip/hip_bf16.h>
#include <cstdint>
#include <cstddef>

#define B_DIM 4
#define L_DIM 2048
#define H_DIM 1024
#define D_DIM 2048
#define N_STATE 16
#define TOKENS (B_DIM * L_DIM)   // 8192
#define NEXT 2176                // GEMM2 N: 2048 dt + 32 B/C + 96 pad (17 tiles of 128)

typedef __bf16 bf16x8 __attribute__((ext_vector_type(8)));
typedef float f32x4 __attribute__((ext_vector_type(4)));

__device__ __forceinline__ float sigmoidf_(float x) { return 1.f / (1.f + __expf(-x)); }
__device__ __forceinline__ float softplusf_(float x) {
  return fmaxf(x, 0.f) + log1pf(__expf(-fabsf(x)));
}
__device__ __forceinline__ void gl_lds16(const void* g, void* l) {
  __builtin_amdgcn_global_load_lds(
      (const __attribute__((address_space(1))) unsigned int*)g,
      (__attribute__((address_space(3))) unsigned int*)l, 16, 0, 0);
}

// ---- shared transpose body (fp32 [R][C] -> bf16 [C][R]), 256-thread block ----
__device__ __forceinline__ void do_transpose(const float* __restrict__ in,
    __hip_bfloat16* __restrict__ out, int R, int C, int c0, int r0, int t) {
  __shared__ float tile[32][33];
  int tx = t & 31, ty = t >> 5;   // 32 x 8
  for (int i = 0; i < 32; i += 8)
    tile[ty + i][tx] = in[(size_t)(r0 + ty + i) * C + c0 + tx];
  __syncthreads();
  for (int i = 0; i < 32; i += 8)
    out[(size_t)(c0 + ty + i) * R + r0 + tx] = __float2bfloat16(tile[tx][ty + i]);
}

// ---------------- merged prep: LN + W_in^T + W_dt^T + W_B/W_C pack -----------
// Block ranges: [0,8192) LN; [8192,12288) W_in transpose; [12288,16384) W_dt
// transpose; [16384,16400) wbc.  One branch per block -> uniform syncthreads.
__global__ __launch_bounds__(256) void prep_kernel(
    const float* __restrict__ x, const float* __restrict__ gamma,
    const float* __restrict__ beta, __hip_bfloat16* __restrict__ xn,
    const float* __restrict__ W_in, __hip_bfloat16* __restrict__ W_inT,
    const float* __restrict__ W_dt, __hip_bfloat16* __restrict__ Wext,
    const float* __restrict__ WB, const float* __restrict__ WC) {
  int b = blockIdx.x;
  int t = threadIdx.x;
  if (b < TOKENS) {
    // ---- LayerNorm -> bf16, one block per token ----
    const float* px = x + (size_t)b * H_DIM;
    float4 v = *(const float4*)(px + t * 4);
    float s  = v.x + v.y + v.z + v.w;
    float ss = v.x * v.x + v.y * v.y + v.z * v.z + v.w * v.w;
    for (int off = 32; off > 0; off >>= 1) {
      s  += __shfl_down(s, off);
      ss += __shfl_down(ss, off);
    }
    __shared__ float red[8];
    __shared__ float stats[2];
    int wave = t >> 6, lane = t & 63;
    if (lane == 0) { red[wave] = s; red[4 + wave] = ss; }
    __syncthreads();
    if (t == 0) {
      float S  = red[0] + red[1] + red[2] + red[3];
      float SS = red[4] + red[5] + red[6] + red[7];
      float mu = S / H_DIM;
      float var = SS / H_DIM - mu * mu;
      stats[0] = mu;
      stats[1] = rsqrtf(var + 1e-5f);
    }
    __syncthreads();
    float mu = stats[0], rstd = stats[1];
    float4 g  = *(const float4*)(gamma + t * 4);
    float4 bt = *(const float4*)(beta + t * 4);
    __hip_bfloat16* po = xn + (size_t)b * H_DIM + t * 4;
    po[0] = __float2bfloat16((v.x - mu) * rstd * g.x + bt.x);
    po[1] = __float2bfloat16((v.y - mu) * rstd * g.y + bt.y);
    po[2] = __float2bfloat16((v.z - mu) * rstd * g.z + bt.z);
    po[3] = __float2bfloat16((v.w - mu) * rstd * g.w + bt.w);
    return;
  }
  b -= TOKENS;
  if (b < 4096) {   // W_in [1024][4096] -> W_inT [4096][1024]
    do_transpose(W_in, W_inT, 1024, 4096, (b & 127) * 32, (b >> 7) * 32, t);
    return;
  }
  b -= 4096;
  if (b < 4096) {   // W_dt [2048][2048] -> Wext rows 0..2047
    do_transpose(W_dt, Wext, 2048, 2048, (b & 63) * 32, (b >> 6) * 32, t);
    return;
  }
  b -= 4096;
  {   // W_B/W_C [2048][16] fp32 -> Wext rows 2048..2079 (transposed)
    int tid = b * 256 + t;   // < 4096
    int c = tid & 31;
    int k0 = (tid >> 5) * 16;
    const float* W = (c < 16) ? WB : WC;
    int cc = c & 15;
    __hip_bfloat16* o = Wext + (size_t)(2048 + c) * D_DIM + k0;
    for (int kk = 0; kk < 16; ++kk)
      o[kk] = __float2bfloat16(W[(size_t)(k0 + kk) * N_STATE + cc]);
  }
}

// ---------------- transpose+convert kernel (W_out, runs after GEMM1) ---------
__global__ void transpose_bf16(const float* __restrict__ in,
                               __hip_bfloat16* __restrict__ out, int R, int C) {
  __shared__ float tile[32][33];
  int c0 = blockIdx.x * 32, r0 = blockIdx.y * 32;
  int tx = threadIdx.x, ty = threadIdx.y;   // (32, 8)
  for (int i = 0; i < 32; i += 8)
    tile[ty + i][tx] = in[(size_t)(r0 + ty + i) * C + c0 + tx];
  __syncthreads();
  for (int i = 0; i < 32; i += 8)
    out[(size_t)(c0 + ty + i) * R + r0 + tx] = __float2bfloat16(tile[tx][ty + i]);
}

// ---------------- bf16 MFMA GEMM: C = A[M,K] @ Bt[N,K]^T ----------------
// 128x128 tile, BK=64, XOR-swizzled LDS (0 conflicts), XCD-aware 1D swizzle.
// T3-minimum double-buffer: per K-step  stage(next) ; compute(cur) ; vmcnt(0) ;
// barrier.  Proven best structure (rounds 3-7).
#define BM 128
#define BN 128
#define BK 64

template <int MODE>
__global__ __launch_bounds__(256) void gemm_bf16(
    const __hip_bfloat16* __restrict__ A, const __hip_bfloat16* __restrict__ Bt,
    void* __restrict__ C0, void* __restrict__ C1, int nsplit,
    int K, int lda, int ldb, int ldc, int gx,
    const float* __restrict__ bias, const float* __restrict__ resid) {
  __shared__ __hip_bfloat16 As[2 * BM * BK];   // 32 KB (double-buffered)
  __shared__ __hip_bfloat16 Bs[2 * BN * BK];   // 32 KB
  int t = threadIdx.x;
  // XCD-aware swizzle
  int bid = blockIdx.x;
  int nsup = gx << 3;
  int super = bid / nsup;
  int rem = bid - super * nsup;
  int m0 = (super * 8 + (rem & 7)) * BM;
  int n0 = (rem >> 3) * BN;

  int wave = t >> 6, lane = t & 63;
  int quad = lane >> 4, l16 = lane & 15;
  int wm = (wave >> 1) * 64, wn = (wave & 1) * 64;

  f32x4 acc[4][4] = {};

  int srow  = t >> 3;            // 0..31
  int cslot = t & 7;
  int cdata = cslot ^ (srow & 7);
  const __hip_bfloat16* Ag[4];
  const __hip_bfloat16* Bg[4];
  int soff[4];
#pragma unroll
  for (int j = 0; j < 4; ++j) {
    Ag[j]  = A  + (size_t)(m0 + j * 32 + srow) * lda + cdata * 8;
    Bg[j]  = Bt + (size_t)(n0 + j * 32 + srow) * ldb + cdata * 8;
    soff[j] = (j * 32 + srow) * BK + cslot * 8;
  }

  const int NT = K / BK;
#pragma unroll
  for (int j = 0; j < 4; ++j) {
    gl_lds16(Ag[j], &As[soff[j]]);
    gl_lds16(Bg[j], &Bs[soff[j]]);
  }
  asm volatile("s_waitcnt vmcnt(0)" ::: "memory");
  __builtin_amdgcn_s_barrier();

  for (int kt = 0; kt < NT; ++kt) {
    const int cur = (kt & 1) * (BM * BK);
    const int nxt = cur ^ (BM * BK);
    if (kt + 1 < NT) {
      const int k1 = (kt + 1) * BK;
#pragma unroll
      for (int j = 0; j < 4; ++j) {
        gl_lds16(Ag[j] + k1, &As[nxt + soff[j]]);
        gl_lds16(Bg[j] + k1, &Bs[nxt + soff[j]]);
      }
    }
#pragma unroll
    for (int s = 0; s < 2; ++s) {
      int cs = ((s * 4 + quad) ^ (l16 & 7)) * 8;
      bf16x8 af[4], bf_[4];
#pragma unroll
      for (int i = 0; i < 4; ++i) {
        af[i]  = *(const bf16x8*)&As[cur + (wm + i * 16 + l16) * BK + cs];
        bf_[i] = *(const bf16x8*)&Bs[cur + (wn + i * 16 + l16) * BK + cs];
      }
#pragma unroll
      for (int i = 0; i < 4; ++i)
#pragma unroll
        for (int j = 0; j < 4; ++j)
          acc[i][j] = __builtin_amdgcn_mfma_f32_16x16x32_bf16(af[i], bf_[j], acc[i][j], 0, 0, 0);
    }
    asm volatile("s_waitcnt vmcnt(0)" ::: "memory");
    __builtin_amdgcn_s_barrier();
  }

#pragma unroll
  for (int i = 0; i < 4; ++i) {
    int row0 = m0 + wm + i * 16 + quad * 4;   // C/D: col=lane&15, row=quad*4+reg
#pragma unroll
    for (int j = 0; j < 4; ++j) {
      int col = n0 + wn + j * 16 + l16;
      f32x4 v = acc[i][j];
      if (MODE == 0) {
#pragma unroll
        for (int r = 0; r < 4; ++r) {
          size_t idx = (size_t)(row0 + r) * ldc + col;
          ((float*)C0)[idx] = v[r] + resid[idx];
        }
      } else if (MODE == 1) {
        bool mainc = (col < nsplit);
        __hip_bfloat16* cb = mainc ? (__hip_bfloat16*)C0 : (__hip_bfloat16*)C1;
        int ccol = mainc ? col : col - nsplit;
#pragma unroll
        for (int r = 0; r < 4; ++r)
          cb[(size_t)(row0 + r) * ldc + ccol] = __float2bfloat16(v[r]);
      } else {
        if (col < nsplit) {
          float bb = bias[col];
#pragma unroll
          for (int r = 0; r < 4; ++r)
            ((__hip_bfloat16*)C0)[(size_t)(row0 + r) * ldc + col] =
                __float2bfloat16(softplusf_(v[r] + bb));
        } else {
#pragma unroll
          for (int r = 0; r < 4; ++r)
            ((float*)C1)[(size_t)(row0 + r) * 128 + (col - nsplit)] = v[r];
        }
      }
    }
  }
}

// ---------------- depthwise conv(3) + SiLU, bf16 in/out ----------------
__global__ __launch_bounds__(256) void conv_silu_kernel(const __hip_bfloat16* __restrict__ xb,
    const float* __restrict__ cw, const float* __restrict__ cb,
    __hip_bfloat16* __restrict__ xbc) {
  size_t i2 = (size_t)blockIdx.x * 256 + threadIdx.x;  // pair index < TOKENS*D_DIM/2
  int dp = (int)(i2 & (D_DIM / 2 - 1));
  size_t tok = i2 >> 10;
  int l = (int)(tok & (L_DIM - 1));
  int d = dp * 2;
  const __hip_bfloat162* base = (const __hip_bfloat162*)xb + i2;
  __hip_bfloat162 cc = base[0];
  float v0 = cw[d * 3 + 1] * __bfloat162float(cc.x) + cb[d];
  float v1 = cw[d * 3 + 4] * __bfloat162float(cc.y) + cb[d + 1];
  if (l > 0) {
    __hip_bfloat162 pm = base[-(D_DIM / 2)];
    v0 += cw[d * 3 + 0] * __bfloat162float(pm.x);
    v1 += cw[d * 3 + 3] * __bfloat162float(pm.y);
  }
  if (l < L_DIM - 1) {
    __hip_bfloat162 pp = base[D_DIM / 2];
    v0 += cw[d * 3 + 2] * __bfloat162float(pp.x);
    v1 += cw[d * 3 + 5] * __bfloat162float(pp.y);
  }
  v0 = v0 * sigmoidf_(v0);
  v1 = v1 * sigmoidf_(v1);
  __hip_bfloat162 o;
  o.x = __float2bfloat16(v0);
  o.y = __float2bfloat16(v1);
  ((__hip_bfloat162*)xbc)[i2] = o;
}

// ============= fused 1-pass scan: one lane per (b, d, n-channel) =============
// Replaces scan1+scan2+scan3.  No chunking: h0 = 0 exact, full-L serial scan.
// 1 exp/step/lane (vs 16 in the per-(d)-thread layout, and 1 pass vs 2).
// y_t = sum_n C[n]*h[n] via 4 shfl_xor over the 16 n-lanes (off the h critical
// path); lane n==0 applies +D*x and the SiLU(z) gate and stores bf16.
// dt/x/z loads are 16-lane same-address broadcasts; B/C loads are 16
// consecutive floats from the 4 MB L2-resident BiCi.  Grid: B*D/16 = 512
// blocks x 256 thr (2048 waves, 2/SIMD); per-step critical path = exp+2 fma.
__global__ __launch_bounds__(256) void scan_fused(
    const __hip_bfloat16* __restrict__ dt, const __hip_bfloat16* __restrict__ xbc,
    const float* __restrict__ BiCi, const float* __restrict__ A_log,
    const __hip_bfloat16* __restrict__ z, const float* __restrict__ Dp,
    __hip_bfloat16* __restrict__ yo) {
  int t = threadIdx.x;
  int n = t & 15;
  int dl = t >> 4;                       // 0..15
  int b = blockIdx.x >> 7;               // 128 blocks per batch
  int d = ((blockIdx.x & 127) << 4) + dl;
  float Aneg = -__expf(A_log[(size_t)d * N_STATE + n]);
  float Dv = Dp[d];
  size_t tb = (size_t)b * L_DIM;
  const __hip_bfloat16* dtp = dt + tb * D_DIM + d;
  const __hip_bfloat16* xp  = xbc + tb * D_DIM + d;
  const __hip_bfloat16* zp  = z + tb * D_DIM + d;
  const float* bp = BiCi + tb * 128 + n;   // [n] = B, [16+n] = C
  __hip_bfloat16* yp = yo + tb * D_DIM + d;

  float h = 0.f;
  float dtv = __bfloat162float(dtp[0]);
  float xv  = __bfloat162float(xp[0]);
  float zv  = __bfloat162float(zp[0]);
  float bv  = bp[0];
  float cv  = bp[16];
  for (int i = 0; i < L_DIM; ++i) {
    int ip = (i < L_DIM - 1) ? i + 1 : i;   // clamped prefetch
    float dt2 = __bfloat162float(dtp[(size_t)ip * D_DIM]);
    float x2  = __bfloat162float(xp[(size_t)ip * D_DIM]);
    float z2  = __bfloat162float(zp[(size_t)ip * D_DIM]);
    float b2  = bp[(size_t)ip * 128];
    float c2  = bp[(size_t)ip * 128 + 16];
    h = __expf(dtv * Aneg) * h + (dtv * xv) * bv;
    float p = h * cv;
    p += __shfl_xor(p, 1);
    p += __shfl_xor(p, 2);
    p += __shfl_xor(p, 4);
    p += __shfl_xor(p, 8);
    if (n == 0) {
      float g = zv * sigmoidf_(zv);
      yp[(size_t)i * D_DIM] = __float2bfloat16((p + Dv * xv) * g);
    }
    dtv = dt2; xv = x2; zv = z2; bv = b2; cv = c2;
  }
}

extern "C" void kernel_launch(void* const* d_in, const int* in_sizes, int n_in,
                              void* d_out, int out_size, void* d_ws, size_t ws_size,
                              hipStream_t stream) {
  const float* x          = (const float*)d_in[0];
  const float* norm_scale = (const float*)d_in[1];
  const float* norm_bias  = (const float*)d_in[2];
  const float* W_in       = (const float*)d_in[3];
  const float* conv_w     = (const float*)d_in[4];
  const float* conv_b     = (const float*)d_in[5];
  const float* W_dt       = (const float*)d_in[6];
  const float* b_dt       = (const float*)d_in[7];
  const float* A_log      = (const float*)d_in[8];
  const float* D_param    = (const float*)d_in[9];
  const float* W_B        = (const float*)d_in[10];
  const float* W_C        = (const float*)d_in[11];
  const float* W_out      = (const float*)d_in[12];
  float* out = (float*)d_out;

  // Workspace layout (193 MB):
  //  S0 [  0, 16M): xn bf16 (dead after GEMM1) -> W_outT [0,4M)
  //  S1 [ 16, 48M): xb bf16 (GEMM1->conv) -> ybf bf16 (scan -> GEMM3)
  //  S2 [ 48, 80M): z bf16 (GEMM1->scan)
  //  S3 [ 80,112M): xbc bf16 (conv->scan)
  //  S4 [112,144M): dt bf16 (GEMM2 main out -> scan)
  //     [144,148M): BiCi fp32 [8192][128] (GEMM2 split out -> scan)
  //     [148,157M): W_ext bf16 [2176][2048] (transposes -> GEMM2)
  //  S6 [177,185M): W_inT bf16 (dead after GEMM1)
  const size_t MB = 1024 * 1024;
  const size_t NEEDED = 193 * MB;
  if (ws_size < NEEDED) return;   // diagnostic bail: ws too small

  char* ws = (char*)d_ws;
  __hip_bfloat16* xn     = (__hip_bfloat16*)(ws);
  __hip_bfloat16* W_outT = (__hip_bfloat16*)(ws);            // [0,4M) after xn dead
  __hip_bfloat16* xb     = (__hip_bfloat16*)(ws + 16 * MB);
  __hip_bfloat16* ybf    = (__hip_bfloat16*)(ws + 16 * MB);  // after conv
  __hip_bfloat16* z      = (__hip_bfloat16*)(ws + 48 * MB);
  __hip_bfloat16* xbc    = (__hip_bfloat16*)(ws + 80 * MB);
  __hip_bfloat16* dtY    = (__hip_bfloat16*)(ws + 112 * MB);
  float*          BiCi   = (float*)(ws + 144 * MB);
  __hip_bfloat16* W_ext  = (__hip_bfloat16*)(ws + 148 * MB);
  __hip_bfloat16* W_inT  = (__hip_bfloat16*)(ws + 177 * MB);

  // 0+1. merged prep: LN + W_in^T + W_dt^T + wbc  (one launch)
  prep_kernel<<<TOKENS + 4096 + 4096 + 16, 256, 0, stream>>>(
      x, norm_scale, norm_bias, xn, W_in, W_inT, W_dt, W_ext, W_B, W_C);
  // 2. merged [xb|z] = xn @ W_in  (MODE 1 split)
  gemm_bf16<1><<<(4096 / BN) * (TOKENS / BM), 256, 0, stream>>>(
      xn, W_inT, xb, z, D_DIM, H_DIM, H_DIM, H_DIM, D_DIM, 4096 / BN,
      nullptr, nullptr);
  // (xn dead) convert W_out into S0
  dim3 tb(32, 8);
  transpose_bf16<<<dim3(1024 / 32, 2048 / 32), tb, 0, stream>>>(W_out, W_outT, 2048, 1024);
  // 3. depthwise conv + silu -> xbc bf16
  conv_silu_kernel<<<(TOKENS * D_DIM / 2) / 256, 256, 0, stream>>>(xb, conv_w, conv_b, xbc);
  // 4. fused: [dt | Bi | Ci] = xbc @ W_ext  (MODE 2: dt bf16+softplus, BiCi fp32)
  gemm_bf16<2><<<(NEXT / BN) * (TOKENS / BM), 256, 0, stream>>>(
      xbc, W_ext, dtY, BiCi, D_DIM, D_DIM, D_DIM, D_DIM, D_DIM, NEXT / BN,
      b_dt, nullptr);
  // 5. fused 1-pass scan + gate (writes ybf; xb region dead)
  scan_fused<<<B_DIM * (D_DIM / 16), 256, 0, stream>>>(
      dtY, xbc, BiCi, A_log, z, D_param, ybf);
  // 6. out = x + y @ W_out   (MODE 0: fp32 + residual)
  gemm_bf16<0><<<(H_DIM / BN) * (TOKENS / BM), 256, 0, stream>>>(
      ybf, W_outT, out, nullptr, 1 << 30, D_DIM, D_DIM, D_DIM, H_DIM, H_DIM / BN,
      nullptr, x);
}

// Round 9
// 568.985 us; speedup vs baseline: 2.1489x; 2.1489x over previous
//
#include <hip/hip_runtime.h>
#include <hip/hip_bf16.h>
#include <cstdint>
#include <cstddef>

#define B_DIM 4
#define L_DIM 2048
#define H_DIM 1024
#define D_DIM 2048
#define N_STATE 16
#define TOKENS (B_DIM * L_DIM)   // 8192
#define CH 32                    // scan chunks
#define LC (L_DIM / CH)          // 64 steps per chunk
#define NEXT 2176                // GEMM2 N: 2048 dt + 32 B/C + 96 pad (17 tiles of 128)
#define CONV_BLKS ((TOKENS * D_DIM / 2) / 256)   // 32768

typedef __bf16 bf16x8 __attribute__((ext_vector_type(8)));
typedef float f32x4 __attribute__((ext_vector_type(4)));

__device__ __forceinline__ float sigmoidf_(float x) { return 1.f / (1.f + __expf(-x)); }
__device__ __forceinline__ float softplusf_(float x) {
  return fmaxf(x, 0.f) + log1pf(__expf(-fabsf(x)));
}
__device__ __forceinline__ void gl_lds16(const void* g, void* l) {
  __builtin_amdgcn_global_load_lds(
      (const __attribute__((address_space(1))) unsigned int*)g,
      (__attribute__((address_space(3))) unsigned int*)l, 16, 0, 0);
}

// ---- shared transpose body (fp32 [R][C] -> bf16 [C][R]), 256-thread block ----
__device__ __forceinline__ void do_transpose(const float* __restrict__ in,
    __hip_bfloat16* __restrict__ out, int R, int C, int c0, int r0, int t) {
  __shared__ float tile[32][33];
  int tx = t & 31, ty = t >> 5;   // 32 x 8
  for (int i = 0; i < 32; i += 8)
    tile[ty + i][tx] = in[(size_t)(r0 + ty + i) * C + c0 + tx];
  __syncthreads();
  for (int i = 0; i < 32; i += 8)
    out[(size_t)(c0 + ty + i) * R + r0 + tx] = __float2bfloat16(tile[tx][ty + i]);
}

// ---------------- merged prep: LN + W_in^T + W_dt^T + W_B/W_C pack -----------
// Block ranges: [0,8192) LN; [8192,12288) W_in transpose; [12288,16384) W_dt
// transpose; [16384,16400) wbc.  One branch per block -> uniform syncthreads.
__global__ __launch_bounds__(256) void prep_kernel(
    const float* __restrict__ x, const float* __restrict__ gamma,
    const float* __restrict__ beta, __hip_bfloat16* __restrict__ xn,
    const float* __restrict__ W_in, __hip_bfloat16* __restrict__ W_inT,
    const float* __restrict__ W_dt, __hip_bfloat16* __restrict__ Wext,
    const float* __restrict__ WB, const float* __restrict__ WC) {
  int b = blockIdx.x;
  int t = threadIdx.x;
  if (b < TOKENS) {
    // ---- LayerNorm -> bf16, one block per token ----
    const float* px = x + (size_t)b * H_DIM;
    float4 v = *(const float4*)(px + t * 4);
    float s  = v.x + v.y + v.z + v.w;
    float ss = v.x * v.x + v.y * v.y + v.z * v.z + v.w * v.w;
    for (int off = 32; off > 0; off >>= 1) {
      s  += __shfl_down(s, off);
      ss += __shfl_down(ss, off);
    }
    __shared__ float red[8];
    __shared__ float stats[2];
    int wave = t >> 6, lane = t & 63;
    if (lane == 0) { red[wave] = s; red[4 + wave] = ss; }
    __syncthreads();
    if (t == 0) {
      float S  = red[0] + red[1] + red[2] + red[3];
      float SS = red[4] + red[5] + red[6] + red[7];
      float mu = S / H_DIM;
      float var = SS / H_DIM - mu * mu;
      stats[0] = mu;
      stats[1] = rsqrtf(var + 1e-5f);
    }
    __syncthreads();
    float mu = stats[0], rstd = stats[1];
    float4 g  = *(const float4*)(gamma + t * 4);
    float4 bt = *(const float4*)(beta + t * 4);
    __hip_bfloat16* po = xn + (size_t)b * H_DIM + t * 4;
    po[0] = __float2bfloat16((v.x - mu) * rstd * g.x + bt.x);
    po[1] = __float2bfloat16((v.y - mu) * rstd * g.y + bt.y);
    po[2] = __float2bfloat16((v.z - mu) * rstd * g.z + bt.z);
    po[3] = __float2bfloat16((v.w - mu) * rstd * g.w + bt.w);
    return;
  }
  b -= TOKENS;
  if (b < 4096) {   // W_in [1024][4096] -> W_inT [4096][1024]
    do_transpose(W_in, W_inT, 1024, 4096, (b & 127) * 32, (b >> 7) * 32, t);
    return;
  }
  b -= 4096;
  if (b < 4096) {   // W_dt [2048][2048] -> Wext rows 0..2047
    do_transpose(W_dt, Wext, 2048, 2048, (b & 63) * 32, (b >> 6) * 32, t);
    return;
  }
  b -= 4096;
  {   // W_B/W_C [2048][16] fp32 -> Wext rows 2048..2079 (transposed)
    int tid = b * 256 + t;   // < 4096
    int c = tid & 31;
    int k0 = (tid >> 5) * 16;
    const float* W = (c < 16) ? WB : WC;
    int cc = c & 15;
    __hip_bfloat16* o = Wext + (size_t)(2048 + c) * D_DIM + k0;
    for (int kk = 0; kk < 16; ++kk)
      o[kk] = __float2bfloat16(W[(size_t)(k0 + kk) * N_STATE + cc]);
  }
}

// ---------------- bf16 MFMA GEMM: C = A[M,K] @ Bt[N,K]^T ----------------
// 128x128 tile, BK=64, XOR-swizzled LDS (0 conflicts), XCD-aware 1D swizzle.
// T3-minimum double-buffer: per K-step  stage(next) ; compute(cur) ; vmcnt(0) ;
// barrier.  Proven best structure (rounds 3-7).
#define BM 128
#define BN 128
#define BK 64

template <int MODE>
__global__ __launch_bounds__(256) void gemm_bf16(
    const __hip_bfloat16* __restrict__ A, const __hip_bfloat16* __restrict__ Bt,
    void* __restrict__ C0, void* __restrict__ C1, int nsplit,
    int K, int lda, int ldb, int ldc, int gx,
    const float* __restrict__ bias, const float* __restrict__ resid) {
  __shared__ __hip_bfloat16 As[2 * BM * BK];   // 32 KB (double-buffered)
  __shared__ __hip_bfloat16 Bs[2 * BN * BK];   // 32 KB
  int t = threadIdx.x;
  // XCD-aware swizzle
  int bid = blockIdx.x;
  int nsup = gx << 3;
  int super = bid / nsup;
  int rem = bid - super * nsup;
  int m0 = (super * 8 + (rem & 7)) * BM;
  int n0 = (rem >> 3) * BN;

  int wave = t >> 6, lane = t & 63;
  int quad = lane >> 4, l16 = lane & 15;
  int wm = (wave >> 1) * 64, wn = (wave & 1) * 64;

  f32x4 acc[4][4] = {};

  int srow  = t >> 3;            // 0..31
  int cslot = t & 7;
  int cdata = cslot ^ (srow & 7);
  const __hip_bfloat16* Ag[4];
  const __hip_bfloat16* Bg[4];
  int soff[4];
#pragma unroll
  for (int j = 0; j < 4; ++j) {
    Ag[j]  = A  + (size_t)(m0 + j * 32 + srow) * lda + cdata * 8;
    Bg[j]  = Bt + (size_t)(n0 + j * 32 + srow) * ldb + cdata * 8;
    soff[j] = (j * 32 + srow) * BK + cslot * 8;
  }

  const int NT = K / BK;
#pragma unroll
  for (int j = 0; j < 4; ++j) {
    gl_lds16(Ag[j], &As[soff[j]]);
    gl_lds16(Bg[j], &Bs[soff[j]]);
  }
  asm volatile("s_waitcnt vmcnt(0)" ::: "memory");
  __builtin_amdgcn_s_barrier();

  for (int kt = 0; kt < NT; ++kt) {
    const int cur = (kt & 1) * (BM * BK);
    const int nxt = cur ^ (BM * BK);
    if (kt + 1 < NT) {
      const int k1 = (kt + 1) * BK;
#pragma unroll
      for (int j = 0; j < 4; ++j) {
        gl_lds16(Ag[j] + k1, &As[nxt + soff[j]]);
        gl_lds16(Bg[j] + k1, &Bs[nxt + soff[j]]);
      }
    }
#pragma unroll
    for (int s = 0; s < 2; ++s) {
      int cs = ((s * 4 + quad) ^ (l16 & 7)) * 8;
      bf16x8 af[4], bf_[4];
#pragma unroll
      for (int i = 0; i < 4; ++i) {
        af[i]  = *(const bf16x8*)&As[cur + (wm + i * 16 + l16) * BK + cs];
        bf_[i] = *(const bf16x8*)&Bs[cur + (wn + i * 16 + l16) * BK + cs];
      }
#pragma unroll
      for (int i = 0; i < 4; ++i)
#pragma unroll
        for (int j = 0; j < 4; ++j)
          acc[i][j] = __builtin_amdgcn_mfma_f32_16x16x32_bf16(af[i], bf_[j], acc[i][j], 0, 0, 0);
    }
    asm volatile("s_waitcnt vmcnt(0)" ::: "memory");
    __builtin_amdgcn_s_barrier();
  }

#pragma unroll
  for (int i = 0; i < 4; ++i) {
    int row0 = m0 + wm + i * 16 + quad * 4;   // C/D: col=lane&15, row=quad*4+reg
#pragma unroll
    for (int j = 0; j < 4; ++j) {
      int col = n0 + wn + j * 16 + l16;
      f32x4 v = acc[i][j];
      if (MODE == 0) {
#pragma unroll
        for (int r = 0; r < 4; ++r) {
          size_t idx = (size_t)(row0 + r) * ldc + col;
          ((float*)C0)[idx] = v[r] + resid[idx];
        }
      } else if (MODE == 1) {
        bool mainc = (col < nsplit);
        __hip_bfloat16* cb = mainc ? (__hip_bfloat16*)C0 : (__hip_bfloat16*)C1;
        int ccol = mainc ? col : col - nsplit;
#pragma unroll
        for (int r = 0; r < 4; ++r)
          cb[(size_t)(row0 + r) * ldc + ccol] = __float2bfloat16(v[r]);
      } else {
        if (col < nsplit) {
          float bb = bias[col];
#pragma unroll
          for (int r = 0; r < 4; ++r)
            ((__hip_bfloat16*)C0)[(size_t)(row0 + r) * ldc + col] =
                __float2bfloat16(softplusf_(v[r] + bb));
        } else {
#pragma unroll
          for (int r = 0; r < 4; ++r)
            ((float*)C1)[(size_t)(row0 + r) * 128 + (col - nsplit)] = v[r];
        }
      }
    }
  }
}

// ------ merged: depthwise conv(3)+SiLU  +  W_out transpose (block-range) -----
// Blocks [0, 32768): conv pair-elements; [32768, 32768+2048): W_out [2048][1024]
// fp32 -> W_outT [1024][2048] bf16 (runs after GEMM1 freed the xn region).
__global__ __launch_bounds__(256) void conv_wout_kernel(
    const __hip_bfloat16* __restrict__ xb, const float* __restrict__ cw,
    const float* __restrict__ cb, __hip_bfloat16* __restrict__ xbc,
    const float* __restrict__ W_out, __hip_bfloat16* __restrict__ W_outT) {
  int blk = blockIdx.x;
  int t = threadIdx.x;
  if (blk >= CONV_BLKS) {
    int b2 = blk - CONV_BLKS;   // < 2048: 32 col-tiles x 64 row-tiles
    do_transpose(W_out, W_outT, 2048, 1024, (b2 & 31) * 32, (b2 >> 5) * 32, t);
    return;
  }
  size_t i2 = (size_t)blk * 256 + t;  // pair index < TOKENS*D_DIM/2
  int dp = (int)(i2 & (D_DIM / 2 - 1));
  size_t tok = i2 >> 10;
  int l = (int)(tok & (L_DIM - 1));
  int d = dp * 2;
  const __hip_bfloat162* base = (const __hip_bfloat162*)xb + i2;
  __hip_bfloat162 cc = base[0];
  float v0 = cw[d * 3 + 1] * __bfloat162float(cc.x) + cb[d];
  float v1 = cw[d * 3 + 4] * __bfloat162float(cc.y) + cb[d + 1];
  if (l > 0) {
    __hip_bfloat162 pm = base[-(D_DIM / 2)];
    v0 += cw[d * 3 + 0] * __bfloat162float(pm.x);
    v1 += cw[d * 3 + 3] * __bfloat162float(pm.y);
  }
  if (l < L_DIM - 1) {
    __hip_bfloat162 pp = base[D_DIM / 2];
    v0 += cw[d * 3 + 2] * __bfloat162float(pp.x);
    v1 += cw[d * 3 + 5] * __bfloat162float(pp.y);
  }
  v0 = v0 * sigmoidf_(v0);
  v1 = v1 * sigmoidf_(v1);
  __hip_bfloat162 o;
  o.x = __float2bfloat16(v0);
  o.y = __float2bfloat16(v1);
  ((__hip_bfloat162*)xbc)[i2] = o;
}

// ---------------- chunked scan phase 1: one THREAD per (b,chunk,d) ----------
// Coalesced: 256 consecutive d per block (round-8 lesson: coalescing, not
// exp-count, dominates scan cost).  BiCi [tok][128]: B = cols 0..15, C = 16..31.
__global__ __launch_bounds__(256) void scan1_kernel(const __hip_bfloat16* __restrict__ dt,
    const __hip_bfloat16* __restrict__ xbc, const float* __restrict__ BiCi,
    const float* __restrict__ A_log, float* __restrict__ hfin,
    float* __restrict__ dtsum) {
  __shared__ float Bsh[LC * N_STATE];   // 4 KB
  int t = threadIdx.x;
  int d = blockIdx.x * 256 + t;
  int c = blockIdx.y, b = blockIdx.z;
  size_t base = (size_t)b * L_DIM + (size_t)c * LC;
  for (int idx = t; idx < LC * 4; idx += 256) {
    int row = idx >> 2, q = idx & 3;
    ((float4*)Bsh)[row * 4 + q] = *(const float4*)&BiCi[(base + row) * 128 + q * 4];
  }
  float Aneg[N_STATE];
  {
    const float4* Ap = (const float4*)(A_log + (size_t)d * N_STATE);
#pragma unroll
    for (int q = 0; q < 4; ++q) {
      float4 av = Ap[q];
      Aneg[4 * q + 0] = -__expf(av.x);
      Aneg[4 * q + 1] = -__expf(av.y);
      Aneg[4 * q + 2] = -__expf(av.z);
      Aneg[4 * q + 3] = -__expf(av.w);
    }
  }
  __syncthreads();
  const __hip_bfloat16* dtp = dt + base * D_DIM + d;
  const __hip_bfloat16* xp = xbc + base * D_DIM + d;
  float h[N_STATE];
#pragma unroll
  for (int n = 0; n < N_STATE; ++n) h[n] = 0.f;
  float ds = 0.f;
  float dtv = __bfloat162float(dtp[0]), xv = __bfloat162float(xp[0]);
  for (int i = 0; i < LC; ++i) {
    int ip = (i < LC - 1) ? i + 1 : i;   // clamped prefetch
    float dt2 = __bfloat162float(dtp[(size_t)ip * D_DIM]);
    float x2  = __bfloat162float(xp[(size_t)ip * D_DIM]);
    float dtx = dtv * xv;
    ds += dtv;
    const float4* Brow = (const float4*)&Bsh[i * N_STATE];
#pragma unroll
    for (int q = 0; q < 4; ++q) {
      float4 bv = Brow[q];
      h[4*q+0] = __expf(dtv * Aneg[4*q+0]) * h[4*q+0] + dtx * bv.x;
      h[4*q+1] = __expf(dtv * Aneg[4*q+1]) * h[4*q+1] + dtx * bv.y;
      h[4*q+2] = __expf(dtv * Aneg[4*q+2]) * h[4*q+2] + dtx * bv.z;
      h[4*q+3] = __expf(dtv * Aneg[4*q+3]) * h[4*q+3] + dtx * bv.w;
    }
    dtv = dt2; xv = x2;
  }
  float* ho = hfin + (((size_t)b * CH + c) * D_DIM + d) * N_STATE;
#pragma unroll
  for (int q = 0; q < 4; ++q) {
    float4 v; v.x = h[4*q]; v.y = h[4*q+1]; v.z = h[4*q+2]; v.w = h[4*q+3];
    ((float4*)ho)[q] = v;
  }
  dtsum[((size_t)b * CH + c) * D_DIM + d] = ds;
}

// ---------------- chunked scan phase 2: combine across chunks ----------------
__global__ __launch_bounds__(256) void scan2_kernel(const float* __restrict__ hfin,
    const float* __restrict__ dtsum, const float* __restrict__ A_log,
    float* __restrict__ hstart) {
  int tid = blockIdx.x * 256 + threadIdx.x;   // < B*D*N = 131072
  int n = tid & 15;
  int d = (tid >> 4) & (D_DIM - 1);
  int b = tid >> 15;
  float Aneg = -__expf(A_log[d * N_STATE + n]);
  float run = 0.f;
  for (int c = 0; c < CH; ++c) {
    size_t o = (((size_t)b * CH + c) * D_DIM + d) * N_STATE + n;
    hstart[o] = run;
    run = __expf(Aneg * dtsum[((size_t)b * CH + c) * D_DIM + d]) * run + hfin[o];
  }
}

// ---------------- chunked scan phase 3: rescan + fused gate ------------------
__global__ __launch_bounds__(256) void scan3_kernel(const __hip_bfloat16* __restrict__ dt,
    const __hip_bfloat16* __restrict__ xbc, const float* __restrict__ BiCi,
    const float* __restrict__ A_log,
    const float* __restrict__ hstart, const __hip_bfloat16* __restrict__ z,
    const float* __restrict__ Dp, __hip_bfloat16* __restrict__ yo) {
  __shared__ float Bsh[LC * N_STATE];   // 4 KB
  __shared__ float Csh[LC * N_STATE];   // 4 KB
  int t = threadIdx.x;
  int d = blockIdx.x * 256 + t;
  int c = blockIdx.y, b = blockIdx.z;
  size_t base = (size_t)b * L_DIM + (size_t)c * LC;
  for (int idx = t; idx < LC * 4; idx += 256) {
    int row = idx >> 2, q = idx & 3;
    ((float4*)Bsh)[row * 4 + q] = *(const float4*)&BiCi[(base + row) * 128 + q * 4];
    ((float4*)Csh)[row * 4 + q] = *(const float4*)&BiCi[(base + row) * 128 + 16 + q * 4];
  }
  float Aneg[N_STATE];
  {
    const float4* Ap = (const float4*)(A_log + (size_t)d * N_STATE);
#pragma unroll
    for (int q = 0; q < 4; ++q) {
      float4 av = Ap[q];
      Aneg[4 * q + 0] = -__expf(av.x);
      Aneg[4 * q + 1] = -__expf(av.y);
      Aneg[4 * q + 2] = -__expf(av.z);
      Aneg[4 * q + 3] = -__expf(av.w);
    }
  }
  float h[N_STATE];
  {
    const float4* hs = (const float4*)(hstart + (((size_t)b * CH + c) * D_DIM + d) * N_STATE);
#pragma unroll
    for (int q = 0; q < 4; ++q) {
      float4 v = hs[q];
      h[4*q] = v.x; h[4*q+1] = v.y; h[4*q+2] = v.z; h[4*q+3] = v.w;
    }
  }
  float Dv = Dp[d];
  __syncthreads();
  const __hip_bfloat16* dtp = dt + base * D_DIM + d;
  const __hip_bfloat16* xp = xbc + base * D_DIM + d;
  const __hip_bfloat16* zp = z + base * D_DIM + d;
  __hip_bfloat16* yp = yo + base * D_DIM + d;
  float dtv = __bfloat162float(dtp[0]), xv = __bfloat162float(xp[0]);
  float zv = __bfloat162float(zp[0]);
  for (int i = 0; i < LC; ++i) {
    int ip = (i < LC - 1) ? i + 1 : i;   // clamped prefetch
    float dt2 = __bfloat162float(dtp[(size_t)ip * D_DIM]);
    float x2  = __bfloat162float(xp[(size_t)ip * D_DIM]);
    float z2  = __bfloat162float(zp[(size_t)ip * D_DIM]);
    float dtx = dtv * xv;
    const float4* Brow = (const float4*)&Bsh[i * N_STATE];
    const float4* Crow = (const float4*)&Csh[i * N_STATE];
    float yv = 0.f;
#pragma unroll
    for (int q = 0; q < 4; ++q) {
      float4 bv = Brow[q];
      float4 cv = Crow[q];
      h[4*q+0] = __expf(dtv * Aneg[4*q+0]) * h[4*q+0] + dtx * bv.x;
      h[4*q+1] = __expf(dtv * Aneg[4*q+1]) * h[4*q+1] + dtx * bv.y;
      h[4*q+2] = __expf(dtv * Aneg[4*q+2]) * h[4*q+2] + dtx * bv.z;
      h[4*q+3] = __expf(dtv * Aneg[4*q+3]) * h[4*q+3] + dtx * bv.w;
      yv += h[4*q+0] * cv.x + h[4*q+1] * cv.y + h[4*q+2] * cv.z + h[4*q+3] * cv.w;
    }
    float g = zv * sigmoidf_(zv);
    yp[(size_t)i * D_DIM] = __float2bfloat16((yv + Dv * xv) * g);
    dtv = dt2; xv = x2; zv = z2;
  }
}

extern "C" void kernel_launch(void* const* d_in, const int* in_sizes, int n_in,
                              void* d_out, int out_size, void* d_ws, size_t ws_size,
                              hipStream_t stream) {
  const float* x          = (const float*)d_in[0];
  const float* norm_scale = (const float*)d_in[1];
  const float* norm_bias  = (const float*)d_in[2];
  const float* W_in       = (const float*)d_in[3];
  const float* conv_w     = (const float*)d_in[4];
  const float* conv_b     = (const float*)d_in[5];
  const float* W_dt       = (const float*)d_in[6];
  const float* b_dt       = (const float*)d_in[7];
  const float* A_log      = (const float*)d_in[8];
  const float* D_param    = (const float*)d_in[9];
  const float* W_B        = (const float*)d_in[10];
  const float* W_C        = (const float*)d_in[11];
  const float* W_out      = (const float*)d_in[12];
  float* out = (float*)d_out;

  // Workspace layout (193 MB):
  //  S0 [  0, 16M): xn bf16 (dead after GEMM1) -> W_outT [0,4M)
  //  S1 [ 16, 48M): xb bf16 (GEMM1->conv) -> ybf bf16 (scan3 -> GEMM3)
  //  S2 [ 48, 80M): z bf16 (GEMM1->scan3)
  //  S3 [ 80,112M): xbc bf16 (conv->scan)
  //  S4 [112,144M): dt bf16 (GEMM2 main out -> scan)
  //     [144,148M): BiCi fp32 [8192][128] (GEMM2 split out -> scan)
  //     [148,157M): W_ext bf16 [2176][2048] (transposes -> GEMM2)
  //     [158,174M): hstart fp32 (16M, CH=32)
  //     [174,175M): dtsum fp32 (1M)
  //  S6 [177,185M): W_inT bf16 (dead after GEMM1) -> hfin fp32 [177,193M) (16M)
  const size_t MB = 1024 * 1024;
  const size_t NEEDED = 193 * MB;
  if (ws_size < NEEDED) return;   // diagnostic bail: ws too small

  char* ws = (char*)d_ws;
  __hip_bfloat16* xn     = (__hip_bfloat16*)(ws);
  __hip_bfloat16* W_outT = (__hip_bfloat16*)(ws);            // [0,4M) after xn dead
  __hip_bfloat16* xb     = (__hip_bfloat16*)(ws + 16 * MB);
  __hip_bfloat16* ybf    = (__hip_bfloat16*)(ws + 16 * MB);  // after conv
  __hip_bfloat16* z      = (__hip_bfloat16*)(ws + 48 * MB);
  __hip_bfloat16* xbc    = (__hip_bfloat16*)(ws + 80 * MB);
  __hip_bfloat16* dtY    = (__hip_bfloat16*)(ws + 112 * MB);
  float*          BiCi   = (float*)(ws + 144 * MB);
  __hip_bfloat16* W_ext  = (__hip_bfloat16*)(ws + 148 * MB);
  float*          hstart = (float*)(ws + 158 * MB);          // 16M
  float*          dtsum  = (float*)(ws + 174 * MB);          // 1M
  __hip_bfloat16* W_inT  = (__hip_bfloat16*)(ws + 177 * MB);
  float*          hfin   = (float*)(ws + 177 * MB);          // 16M after W_inT dead

  // 0+1. merged prep: LN + W_in^T + W_dt^T + wbc  (one launch)
  prep_kernel<<<TOKENS + 4096 + 4096 + 16, 256, 0, stream>>>(
      x, norm_scale, norm_bias, xn, W_in, W_inT, W_dt, W_ext, W_B, W_C);
  // 2. merged [xb|z] = xn @ W_in  (MODE 1 split)
  gemm_bf16<1><<<(4096 / BN) * (TOKENS / BM), 256, 0, stream>>>(
      xn, W_inT, xb, z, D_DIM, H_DIM, H_DIM, H_DIM, D_DIM, 4096 / BN,
      nullptr, nullptr);
  // 3. merged: depthwise conv + silu -> xbc  AND  W_out^T -> W_outT (xn dead)
  conv_wout_kernel<<<CONV_BLKS + 2048, 256, 0, stream>>>(
      xb, conv_w, conv_b, xbc, W_out, W_outT);
  // 4. fused: [dt | Bi | Ci] = xbc @ W_ext  (MODE 2: dt bf16+softplus, BiCi fp32)
  gemm_bf16<2><<<(NEXT / BN) * (TOKENS / BM), 256, 0, stream>>>(
      xbc, W_ext, dtY, BiCi, D_DIM, D_DIM, D_DIM, D_DIM, D_DIM, NEXT / BN,
      b_dt, nullptr);
  // 5. chunked scan: local -> combine -> rescan+gate (writes ybf, xb region dead)
  scan1_kernel<<<dim3(D_DIM / 256, CH, B_DIM), 256, 0, stream>>>(
      dtY, xbc, BiCi, A_log, hfin, dtsum);
  scan2_kernel<<<(B_DIM * D_DIM * N_STATE) / 256, 256, 0, stream>>>(
      hfin, dtsum, A_log, hstart);
  scan3_kernel<<<dim3(D_DIM / 256, CH, B_DIM), 256, 0, stream>>>(
      dtY, xbc, BiCi, A_log, hstart, z, D_param, ybf);
  // 6. out = x + y @ W_out   (MODE 0: fp32 + residual)
  gemm_bf16<0><<<(H_DIM / BN) * (TOKENS / BM), 256, 0, stream>>>(
      ybf, W_outT, out, nullptr, 1 << 30, D_DIM, D_DIM, D_DIM, H_DIM, H_DIM / BN,
      nullptr, x);
}